// Round 9
// baseline (112.185 us; speedup 1.0000x reference)
//
#include <hip/hip_runtime.h>
#include <hip/hip_bf16.h>

#define SELF_D 36
#define ENT_D  28
#define HID    256
#define OBS    1688   // 36 + 28*59 ; 422 float4s
#define NWAVES 8192   // pool: 2048 blocks x 4 waves, wave-per-row

// ws float layout
#define WS_A     0        // 36*256 (k-major)
#define WS_B     9216     // 28*256
#define WS_C     16384    // 256
#define WS_MSEL  16640    // 108  } contiguous 360 = Mfull[120][3]
#define WS_MENT  16748    // 252
#define WS_CG    17000    // 3
#define WS_WATT  17008    // 28
#define WS_AT    17040    // 256*36 c-major AT[c][k]
#define WS_BT    26256    // 256*28 c-major BT[c][k]
#define WS_TOTAL 33424

__global__ __launch_bounds__(256)
void setup_kernel(const float* __restrict__ Watt, const float* __restrict__ We,
                  const float* __restrict__ be,  const float* __restrict__ Wse,
                  const float* __restrict__ bse, const float* __restrict__ Wg,
                  const float* __restrict__ bg,  const float* __restrict__ Wo,
                  const float* __restrict__ bo,  float* __restrict__ ws) {
  const int blk = blockIdx.x;
  const int c = threadIdx.x;
  if (blk < 36) {
    int k = blk;
    float acc = 0.f;
    for (int r = 0; r < 256; ++r) acc += We[k*256 + r] * Wo[r*256 + c];
    for (int r = 0; r < 256; ++r) acc += (Wse[k*256 + r] + Wse[(36+k)*256 + r]) * Wo[(256+r)*256 + c];
    ws[WS_A + k*256 + c] = acc;
    ws[WS_AT + c*36 + k] = acc;
  } else if (blk < 64) {
    int k = blk - 36;
    float acc = 0.f;
    for (int r = 0; r < 256; ++r) acc += We[(36+k)*256 + r] * Wo[r*256 + c];
    ws[WS_B + k*256 + c] = acc;
    ws[WS_BT + c*28 + k] = acc;
  } else if (blk == 64) {
    float acc = bo[c];
    for (int r = 0; r < 256; ++r) acc += be[r] * Wo[r*256 + c];
    for (int r = 0; r < 256; ++r) acc += bse[r] * Wo[(256+r)*256 + c];
    ws[WS_C + c] = acc;
  } else {
    for (int t = c; t < 391; t += 256) {
      if (t < 108) {
        int k = t / 3, j = t - 3*k;
        float acc = 0.f;
        for (int r = 0; r < 256; ++r) {
          float wg = Wg[r*3 + j] + Wg[(256+r)*3 + j] + Wg[(512+r)*3 + j];
          acc += We[k*256 + r] * wg;
        }
        ws[WS_MSEL + t] = acc;
      } else if (t < 360) {
        int idx = t - 108;
        int g = idx / 84, rem = idx - 84*g;
        int k = rem / 3, j = rem - 3*k;
        float acc = 0.f;
        for (int r = 0; r < 256; ++r) acc += We[(36+k)*256 + r] * Wg[(256*g + r)*3 + j];
        ws[WS_MENT + idx] = acc;
      } else if (t < 363) {
        int j = t - 360;
        float acc = bg[j];
        for (int r = 0; r < 256; ++r)
          acc += be[r] * (Wg[r*3 + j] + Wg[(256+r)*3 + j] + Wg[(512+r)*3 + j]);
        ws[WS_CG + j] = acc;
      } else {
        int k = t - 363;
        ws[WS_WATT + k] = Watt[36 + k];
      }
    }
  }
}

// exact RNE f32->bf16 pack of two floats into one u32 (low = a, high = b)
__device__ __forceinline__ unsigned pack_bf2(float a, float b) {
  unsigned ua = __float_as_uint(a);
  unsigned ub = __float_as_uint(b);
  ua = (ua + 0x7fffu + ((ua >> 16) & 1u)) >> 16;
  ub = (ub + 0x7fffu + ((ub >> 16) & 1u)) & 0xffff0000u;
  return ua | ub;
}
__device__ __forceinline__ float bf_lo(unsigned u) { return __uint_as_float(u << 16); }
__device__ __forceinline__ float bf_hi(unsigned u) { return __uint_as_float(u & 0xffff0000u); }
__device__ __forceinline__ float bperm(int idx4, float v) {
  return __int_as_float(__builtin_amdgcn_ds_bpermute(idx4, __float_as_int(v)));
}

// Wave-per-row, barrier-free, bf16 LDS tile (56B rows), f32 accumulation.
// Slots: slot = g*20 + i; slot 39 = DUMMY (row zeroed once; att=0 keeps it 0).
// Per row: {stage pf->tile(bf16); issue next pf; logits (E kept in regs);
// softmax in regs (6 max-shfl + 5 windowed bpermute rotate-sums); premult
// v=att_n*E written back; 4-comp means via b64; gate (weights hoisted); emit}.
__global__ __launch_bounds__(256)
void pool_kernel(const float* __restrict__ x, const float* __restrict__ ws,
                 float* __restrict__ out, int B) {
  __shared__ __align__(16) unsigned short tileh[4][60*28]; // bf16, 3360B/wave
  __shared__ __align__(16) float sself[4][40];
  __shared__ __align__(16) float sebar[4][88];

  const int tid = threadIdx.x;
  const int w = tid >> 6, ln = tid & 63;

  // one-time: zero dummy row 39 (per-wave; no block barrier needed)
  if (ln < 7) ((uint2*)&tileh[w][39*28])[ln] = make_uint2(0u, 0u);

  const float* Wp = ws + WS_WATT;   // uniform -> SGPR loads
  const float cg0 = ws[WS_CG + 0], cg1 = ws[WS_CG + 1], cg2 = ws[WS_CG + 2];

  // ---- row-invariant per-lane constants ----
  int  soff[7]; bool went[7];
#pragma unroll
  for (int i = 0; i < 7; ++i) {
    int q = i*64 + ln;
    bool v = (q >= 9) && (q < 422);
    went[i] = v;
    int qm = v ? (q - 9) : 0;
    int e = qm / 7, t = qm - 7*e;
    int s = e + (e >= 39 ? 1 : 0);
    soff[i] = s*28 + 4*t;
  }
  const bool wself = (ln < 9);

  const bool lval = (ln < 60) && (ln != 39);
  const int  lrow = (ln < 60 ? ln : 0) * 28;

  // rotate-by-r bpermute byte-indices within 20-slot group (lanes>=60: self-group of 4)
  int rotb[5];
  {
    int base = (ln < 60) ? (ln/20)*20 : 60;
    int n    = (ln < 60) ? 20 : 4;
    int off  = ln - base;
    const int rs[5] = {1, 2, 4, 8, 16};
#pragma unroll
    for (int j = 0; j < 5; ++j) rotb[j] = (base + (off + rs[j]) % n) * 4;
  }

  const bool mact = (ln < 21);
  const int  mg = ln / 7, mkq = ln - 7*mg;      // group, 4-comp quad
  const int  mrow0 = (mg*20)*28 + 4*mkq;

  const int  gj = ln >> 4, gch = ln & 15;
  const bool gact = (gj < 3) && (gch < 15);
  float gw8[8];                                  // hoisted gate weights
#pragma unroll
  for (int q = 0; q < 8; ++q)
    gw8[q] = gact ? ws[WS_MSEL + (q*15 + gch)*3 + gj] : 0.f;

  const int row0 = blockIdx.x * 4 + w;

  // prologue: first row into pf (coalesced float4)
  float4 pf[7];
  if (row0 < B) {
    const float4* xr = (const float4*)(x + (size_t)row0 * OBS);
#pragma unroll
    for (int i = 0; i < 7; ++i) { int idx = i*64 + ln; if (idx < 422) pf[i] = xr[idx]; }
  }

  for (int row = row0; row < B; row += NWAVES) {
    // (1) stage: pf -> bf16 tile (7 x 8B writes) + self f32
    if (wself) *(float4*)&sself[w][ln*4] = pf[0];
#pragma unroll
    for (int i = 0; i < 7; ++i) {
      if (went[i]) {
        uint2 u = make_uint2(pack_bf2(pf[i].x, pf[i].y), pack_bf2(pf[i].z, pf[i].w));
        *(uint2*)&tileh[w][soff[i]] = u;
      }
    }

    // (2) issue next row's loads (fly across all compute below)
    {
      int nr = row + NWAVES;
      if (nr < B) {
        const float4* xn = (const float4*)(x + (size_t)nr * OBS);
#pragma unroll
        for (int i = 0; i < 7; ++i) { int idx = i*64 + ln; if (idx < 422) pf[i] = xn[idx]; }
      }
    }
    asm volatile("" ::: "memory");   // compile-time order: stage writes before reads

    // (3) attention logits; keep E (f32) in regs for premult
    float4 ev[7];
    float l = -1e30f;
    {
      float acc = 0.f;
#pragma unroll
      for (int t = 0; t < 7; ++t) {
        uint2 u = *(const uint2*)&tileh[w][lrow + 4*t];
        ev[t].x = bf_lo(u.x); ev[t].y = bf_hi(u.x);
        ev[t].z = bf_lo(u.y); ev[t].w = bf_hi(u.y);
        acc += ev[t].x*Wp[4*t] + ev[t].y*Wp[4*t+1] + ev[t].z*Wp[4*t+2] + ev[t].w*Wp[4*t+3];
      }
      if (lval) l = acc;
    }

    // (4) softmax in registers: row max (shift-safe), exp, group-sum via rotations
    float m = l;
#pragma unroll
    for (int off = 32; off; off >>= 1) m = fmaxf(m, __shfl_xor(m, off));
    float a = lval ? __expf(l - m) : 0.f;
    float w2  = a  + bperm(rotb[0], a);
    float w4  = w2 + bperm(rotb[1], w2);
    float w8  = w4 + bperm(rotb[2], w4);
    float w16 = w8 + bperm(rotb[3], w8);
    float us  = w16 + bperm(rotb[4], w4);   // window 16 + 4 = exact 20-sum
    float an  = a / us;

    // (5) premultiplied values back to tile: v = att_n * E  (row 39 -> zeros)
    if (ln < 60) {
#pragma unroll
      for (int t = 0; t < 7; ++t) {
        uint2 u = make_uint2(pack_bf2(ev[t].x*an, ev[t].y*an),
                             pack_bf2(ev[t].z*an, ev[t].w*an));
        *(uint2*)&tileh[w][lrow + 4*t] = u;
      }
    }
    asm volatile("" ::: "memory");

    // (6) means: lane = (g, quad) sums 20 slots x 4 comps (b64 reads)
    if (mact) {
      float s0 = 0.f, s1 = 0.f, s2 = 0.f, s3 = 0.f;
#pragma unroll
      for (int i = 0; i < 20; ++i) {
        uint2 u = *(const uint2*)&tileh[w][mrow0 + i*28];
        s0 += bf_lo(u.x); s1 += bf_hi(u.x);
        s2 += bf_lo(u.y); s3 += bf_hi(u.y);
      }
      *(float4*)&sebar[w][mg*28 + 4*mkq] = make_float4(s0, s1, s2, s3);
    }
    asm volatile("" ::: "memory");

    // (7) gate logits: lanes (j<3, ch<15), weights in regs; f from LDS
    float gl = 0.f;
    if (gact) {
#pragma unroll
      for (int q = 0; q < 8; ++q) {
        int c = q*15 + gch;
        float v = (c < SELF_D) ? sself[w][c] : sebar[w][c - SELF_D];
        gl += v * gw8[q];
      }
    }
#pragma unroll
    for (int off = 1; off < 16; off <<= 1) gl += __shfl_xor(gl, off);
    float l0 = __shfl(gl, 0)  + cg0;
    float l1 = __shfl(gl, 16) + cg1;
    float l2 = __shfl(gl, 32) + cg2;
    float mm = fmaxf(l0, fmaxf(l1, l2));
    float e0x = __expf(l0 - mm), e1x = __expf(l1 - mm), e2x = __expf(l2 - mm);
    float inv = 1.f / (e0x + e1x + e2x);

    // (8) emit f = [self(36), gated-mix(28)]
    float fv;
    if (ln < SELF_D) {
      fv = sself[w][ln];
    } else {
      int k = ln - SELF_D;
      fv = (e0x * sebar[w][k] + e1x * sebar[w][28 + k] + e2x * sebar[w][56 + k]) * inv;
    }
    out[(size_t)row * HID + ln] = fv;
  }
}

// out[row][c] = cc[c] + f[0:36]@AT[c] + f[36:64]@BT[c]; f in-place from out[row][0:64].
#define PR_ROWS 32
#define PR_CH   8
__global__ __launch_bounds__(256)
void proj_kernel(const float* __restrict__ ws, float* __restrict__ out) {
  __shared__ __align__(16) float sf[PR_CH][64];
  const int tid = threadIdx.x;

  float4 Av[9], Bv[7];
#pragma unroll
  for (int q = 0; q < 9; ++q) Av[q] = ((const float4*)(ws + WS_AT + tid * 36))[q];
#pragma unroll
  for (int q = 0; q < 7; ++q) Bv[q] = ((const float4*)(ws + WS_BT + tid * 28))[q];
  const float cc = ws[WS_C + tid];

  const size_t row0 = (size_t)blockIdx.x * PR_ROWS;
  for (int chk = 0; chk < PR_ROWS / PR_CH; ++chk) {
    const size_t rbase = row0 + chk * PR_CH;
    if (tid < PR_CH * 16) {
      int r = tid >> 4, q = tid & 15;
      ((float4*)&sf[r][0])[q] = ((const float4*)(out + (rbase + r) * HID))[q];
    }
    __syncthreads();
#pragma unroll
    for (int r = 0; r < PR_CH; ++r) {
      float acc = cc;
      const float4* f4 = (const float4*)&sf[r][0];
#pragma unroll
      for (int q = 0; q < 9; ++q) {
        float4 s = f4[q];
        acc += Av[q].x*s.x + Av[q].y*s.y + Av[q].z*s.z + Av[q].w*s.w;
      }
#pragma unroll
      for (int q = 0; q < 7; ++q) {
        float4 s = f4[9 + q];
        acc += Bv[q].x*s.x + Bv[q].y*s.y + Bv[q].z*s.z + Bv[q].w*s.w;
      }
      out[(rbase + r) * HID + tid] = acc;
    }
    __syncthreads();
  }
}

extern "C" void kernel_launch(void* const* d_in, const int* in_sizes, int n_in,
                              void* d_out, int out_size, void* d_ws, size_t ws_size,
                              hipStream_t stream) {
  const float* x    = (const float*)d_in[0];
  const float* Watt = (const float*)d_in[1];
  const float* We   = (const float*)d_in[3];
  const float* be   = (const float*)d_in[4];
  const float* Wse  = (const float*)d_in[5];
  const float* bse  = (const float*)d_in[6];
  const float* Wg   = (const float*)d_in[7];
  const float* bg   = (const float*)d_in[8];
  const float* Wo   = (const float*)d_in[9];
  const float* bo   = (const float*)d_in[10];
  float* out = (float*)d_out;
  float* ws  = (float*)d_ws;
  const int B = in_sizes[0] / OBS;

  setup_kernel<<<66, 256, 0, stream>>>(Watt, We, be, Wse, bse, Wg, bg, Wo, bo, ws);
  pool_kernel<<<NWAVES / 4, 256, 0, stream>>>(x, ws, out, B);
  proj_kernel<<<B / PR_ROWS, 256, 0, stream>>>(ws, out);
}